// Round 15
// baseline (4690.976 us; speedup 1.0000x reference)
//
#include <hip/hip_runtime.h>
#include <math.h>

#define BATCH 512
#define LOG2PI 1.8378770664093453f
#define HB 262144   // 512*512 shorts

typedef __attribute__((ext_vector_type(8))) short bfrag;   // 8 bf16
typedef __attribute__((ext_vector_type(4))) float f32x4;
typedef __attribute__((ext_vector_type(4))) unsigned int u32x4;

#define MFMA(a,b,c) __builtin_amdgcn_mfma_f32_16x16x32_bf16(a,b,c,0,0,0)
#define ASTORE(p,v) __hip_atomic_store((p),(v),__ATOMIC_RELAXED,__HIP_MEMORY_SCOPE_AGENT)
#define ALOAD(p)    __hip_atomic_load((p),__ATOMIC_RELAXED,__HIP_MEMORY_SCOPE_AGENT)

// sc1 16B store: lands at L3, visible cross-XCD after vmcnt drain (r6-12 proven)
__device__ __forceinline__ void st16_sc1(void* p, u32x4 v){
  asm volatile("global_store_dwordx4 %0, %1, off sc1" :: "v"(p), "v"(v) : "memory");
}
// volatile 16B load: reads L3 coherence point (r9 proven, no fence needed)
__device__ __forceinline__ bfrag vlb(const unsigned short* p){
  u32x4 v = *(const volatile u32x4*)p;
  union { u32x4 u; bfrag b; } c; c.u = v; return c.b;
}

__device__ __forceinline__ float sigm(float x){ return 1.0f/(1.0f+__expf(-x)); }
__device__ __forceinline__ unsigned short f2bf(float f){
  unsigned int u = __builtin_bit_cast(unsigned int, f);
  u += 0x7FFFu + ((u>>16)&1u);          // RNE
  return (unsigned short)(u>>16);
}
__device__ __forceinline__ bfrag cvt8(const float* __restrict__ p){
  bfrag v;
  #pragma unroll
  for (int e=0;e<8;++e) v[e] = (short)f2bf(p[e]);
  return v;
}
__device__ __forceinline__ bfrag cvt8d(const float* __restrict__ p1, const float* __restrict__ p0){
  bfrag v;
  #pragma unroll
  for (int e=0;e<8;++e) v[e] = (short)f2bf(p1[e]-p0[e]);
  return v;
}

struct Params {
  const float *states, *zin;
  const float *Wih0, *Whh0, *bih0, *bhh0;
  const float *Wih1, *Whh1, *bih1, *bhh1;
  const float *Wfc1, *bfc1, *Wfc2, *bfc2;
  const float *Wmean, *bmean, *Wlv, *blv;
  unsigned short *act;
  float *out;
};

// arena (shorts, 18HB = 9.4MB + flags):
//   h0G 0..4HB | h1G 4..8HB | d1G 8..12HB   (sc1 4-deep, cross-XCD, volatile-read)
//   h0L 12..14HB | h1L 14..16HB | d2L 16..18HB (plain 2-deep, intra-XCD)
// Roles (xg=blk&7, sub=blk>>3) identical to r12. Flags: sc1 only, value u+1
// after iter u. All waits reference PREVIOUS-iteration completions -> no
// same-phase cycles -> deadlock-free. L1-only buffer_inv per phase; no agent
// fence (no plain read ever targets cross-XCD data).
__global__ __launch_bounds__(256, 1) void fused(Params P, unsigned* flags) {
  __shared__ unsigned short sm[74752];   // 149504 B static LDS
  const int tid  = threadIdx.x;
  const int lane = tid & 63;
  const int wv   = tid >> 6;
  const int r16  = lane & 15, kg = lane >> 4;
  const int blk  = blockIdx.x;
  const int xg   = blk & 7, sub = blk >> 3;

  unsigned short* h0G = P.act;
  unsigned short* h1G = P.act +  4*(size_t)HB;
  unsigned short* d1G = P.act +  8*(size_t)HB;
  unsigned short* h0L = P.act + 12*(size_t)HB;
  unsigned short* h1L = P.act + 14*(size_t)HB;
  unsigned short* d2L = P.act + 16*(size_t)HB;

  // ---------------- startup: stage weights (+z) into LDS (bf16) -----------
  if (xg < 4) {
    const int jt = sub;
    const float* Wsrc[2] = {P.Wih1, P.Whh1};
    #pragma unroll
    for (int m = 0; m < 2; ++m) {
      const float* W = Wsrc[m];
      for (int c = tid; c < 3072; c += 256) {
        int g = c >> 10, rem = c & 1023;
        int r = rem >> 6, k = (rem & 63) << 3;
        *(bfrag*)&sm[(g*16+r)*1032 + m*512 + k] =
          cvt8(&W[((size_t)(g*512 + jt*16 + r))*512 + k]);
      }
    }
  } else if (xg < 6) {
    const int jt = sub;
    for (int c = tid; c < 384; c += 256) {
      int g = c >> 7, rem = c & 127;
      int r = rem >> 3, k = (rem & 7) << 3;
      *(bfrag*)&sm[(g*16+r)*584 + k] =
        cvt8(&P.Wih0[((size_t)(g*512 + jt*16 + r))*64 + k]);
    }
    for (int c = tid; c < 3072; c += 256) {
      int g = c >> 10, rem = c & 1023;
      int r = rem >> 6, k = (rem & 63) << 3;
      *(bfrag*)&sm[(g*16+r)*584 + 64 + k] =
        cvt8(&P.Whh0[((size_t)(g*512 + jt*16 + r))*512 + k]);
    }
  } else if (xg == 6) {
    const int bn = (sub & 7) * 64;
    const int bmB = (sub >> 3) * 128;
    for (int c = tid; c < 4864; c += 256) {
      int n = c / 76, k = (c % 76) << 3;
      *(bfrag*)&sm[n*616 + k] = cvt8(&P.Wfc1[(size_t)(bn + n)*608 + k]);
    }
    for (int c = tid; c < 1024; c += 256) {      // z slice rows bmB..bmB+127
      int r = c >> 3, k = (c & 7) << 3;
      *(bfrag*)&sm[47616 + r*64 + k] = cvt8(&P.zin[(size_t)(bmB + r)*64 + k]);
    }
  } else {
    const int bn = (sub & 7) * 64;
    for (int c = tid; c < 4096; c += 256) {
      int n = c >> 6, k = (c & 63) << 3;
      *(bfrag*)&sm[n*520 + k] = cvt8(&P.Wfc2[(size_t)(bn + n)*512 + k]);
    }
    for (int c = tid; c < 4096; c += 256) {
      int m = c >> 6, k = (c & 63) << 3;
      const float* src = (m < 32) ? &P.Wmean[(size_t)m*512 + k]
                                  : &P.Wlv[(size_t)(m-32)*512 + k];
      *(bfrag*)&sm[33280 + m*520 + k] = cvt8(src);
    }
  }

  // ---------------- hoisted per-thread biases ----------------
  float b0 = 0.f, b1 = 0.f, b2 = 0.f, b3 = 0.f;
  if (xg < 4) {
    int j = sub*16 + r16;
    b0 = P.bih1[j] + P.bhh1[j];
    b1 = P.bih1[j+512] + P.bhh1[j+512];
    b2 = P.bih1[j+1024]; b3 = P.bhh1[j+1024];
  } else if (xg < 6) {
    int j = sub*16 + r16;
    b0 = P.bih0[j] + P.bhh0[j];
    b1 = P.bih0[j+512] + P.bhh0[j+512];
    b2 = P.bih0[j+1024]; b3 = P.bhh0[j+1024];
  } else if (xg == 6) {
    int nn0 = (sub & 7)*64 + (wv&1)*32 + r16;
    b0 = P.bfc1[nn0]; b1 = P.bfc1[nn0+16];
  } else {
    int nn0 = (sub & 7)*64 + (wv&1)*32 + r16;
    b0 = P.bfc2[nn0]; b1 = P.bfc2[nn0+16];
    int c = wv*16 + r16;
    b2 = (c < 32) ? P.bmean[c] : P.blv[c-32];
  }
  float hs[4][4] = {};                  // gru f32 master state (regs)
  float nacc0 = 0.f, nacc1 = 0.f;

  for (int u = 0; u <= 256; ++u) {
    // ---------------- dataflow wait (all prev-iteration edges) ----------------
    if (wv == 0) {
      int pA=-1, pB=-1, pC=-1; unsigned tA=0, tB=0, tC=0;
      if (xg >= 4 && xg < 6) {                       // gru0
        if (u >= 1 && lane < 32) { pA = lane*8 + xg; tA = u; }      // own grp (h0L)
        if (u >= 4) {                                               // WAR h0G: gru1>=u-2
          int s = lane & 31, x0 = (lane >> 5) * 2;
          pB = s*8 + x0;     tB = u-2;
          pC = s*8 + x0 + 1; tC = u-2;
        }
      } else if (xg < 4) {                           // gru1
        if (u >= 1) {
          if (lane < 32) { pA = lane*8 + xg; tA = u; }              // own grp (h1L)
          else           { pB = (lane-32)*8 + 4 + (xg>>1); tB = u; }// gru0 grp (h0G RAW)
        }
        if (u >= 5 && lane < 8) { pC = (xg*8 + lane)*8 + 6; tC = u-2; } // WAR h1G: fc1
      } else if (xg == 6) {                          // fc1
        if (u >= 1 && lane < 32) { pA = lane*8 + (sub>>3); tA = u; }   // gru1 grp (h1G RAW)
        if (u >= 5 && lane >= 32) { pB = (lane-32)*8 + 7; tB = u-2; }  // WAR d1G: fc2
      } else {                                       // fc2/head
        if (u >= 2) {
          if (lane < 8)   { pA = ((sub & ~7) + lane)*8 + 6; tA = u; }  // fc1 (d1G RAW)
          if (lane >= 32 && lane < 40)
                          { pB = ((sub & ~7) + (lane-32))*8 + 7; tB = u; } // own grp (d2L)
        }
      }
      unsigned spin = 0;
      while (true) {
        bool ok = true;
        if (pA >= 0) ok &= (ALOAD(&flags[pA*16]) >= tA);
        if (pB >= 0) ok &= (ALOAD(&flags[pB*16]) >= tB);
        if (pC >= 0) ok &= (ALOAD(&flags[pC*16]) >= tC);
        if (__all(ok)) break;
        if (++spin > (1u<<20)) break;                // safety: ~0.1s cap
        __builtin_amdgcn_s_sleep(1);
      }
    }
    __syncthreads();
    if (tid < 64) asm volatile("buffer_inv\n\ts_waitcnt vmcnt(0)" ::: "memory"); // L1 only
    __syncthreads();

    if (xg < 4) {
      // ---------------- gru1, step t = u-1 ----------------
      if (u >= 1 && u <= 254) {
        const int jt = sub, bmB = xg * 128;
        const unsigned short* h0r = h0G + (size_t)((u+3)&3)*HB;   // h0(u-1), L3
        const unsigned short* h1r = h1L + (size_t)(u&1)*HB;       // h1(u-2), local L2
        f32x4 R[2]={}, Z[2]={}, NI[2]={}, NH[2]={};
        const int row0 = bmB + wv*32 + r16;
        #pragma unroll 4
        for (int kt = 0; kt < 16; ++kt) {            // half 0: h0 (volatile L3)
          const int kk = kt*32 + kg*8;
          bfrag a0 = vlb(h0r + (size_t)row0*512 + kk);
          bfrag a1 = vlb(h0r + (size_t)(row0+16)*512 + kk);
          bfrag bR = *(const bfrag*)&sm[(0*16+r16)*1032 + kk];
          bfrag bZ = *(const bfrag*)&sm[(1*16+r16)*1032 + kk];
          bfrag bN = *(const bfrag*)&sm[(2*16+r16)*1032 + kk];
          R[0]=MFMA(a0,bR,R[0]); R[1]=MFMA(a1,bR,R[1]);
          Z[0]=MFMA(a0,bZ,Z[0]); Z[1]=MFMA(a1,bZ,Z[1]);
          NI[0]=MFMA(a0,bN,NI[0]); NI[1]=MFMA(a1,bN,NI[1]);
        }
        #pragma unroll 4
        for (int kt = 0; kt < 16; ++kt) {            // half 1: h1 (plain L2)
          const int kk = kt*32 + kg*8;
          const int kl = 512 + kk;
          bfrag a0 = *(const bfrag*)&h1r[(size_t)row0*512 + kk];
          bfrag a1 = *(const bfrag*)&h1r[(size_t)(row0+16)*512 + kk];
          bfrag bR = *(const bfrag*)&sm[(0*16+r16)*1032 + kl];
          bfrag bZ = *(const bfrag*)&sm[(1*16+r16)*1032 + kl];
          bfrag bN = *(const bfrag*)&sm[(2*16+r16)*1032 + kl];
          R[0]=MFMA(a0,bR,R[0]); R[1]=MFMA(a1,bR,R[1]);
          Z[0]=MFMA(a0,bZ,Z[0]); Z[1]=MFMA(a1,bZ,Z[1]);
          NH[0]=MFMA(a0,bN,NH[0]); NH[1]=MFMA(a1,bN,NH[1]);
        }
        unsigned short* exch = sm + 49536;          // [128][16]
        #pragma unroll
        for (int fm = 0; fm < 2; ++fm)
          #pragma unroll
          for (int e = 0; e < 4; ++e) {
            int rl = wv*32 + fm*16 + kg*4 + e;
            float r  = sigm(R[fm][e] + b0);
            float zg = sigm(Z[fm][e] + b1);
            float nn = tanhf(NI[fm][e] + b2 + r*(NH[fm][e] + b3));
            float hn = (1.f - zg)*nn + zg*hs[fm][e];
            hs[fm][e] = hn;
            exch[rl*16 + r16] = f2bf(hn);
          }
        __syncthreads();
        {
          int r = tid >> 1, hc = tid & 1;
          u32x4 v = *(const u32x4*)&exch[r*16 + hc*8];
          size_t off = ((size_t)(bmB + r))*512 + jt*16 + hc*8;
          *(u32x4*)&h1L[(size_t)((u+1)&1)*HB + off] = v;      // local recurrence
          st16_sc1(h1G + (size_t)((u+3)&3)*HB + off, v);      // cross-XCD (fc1)
        }
      }
    } else if (xg < 6) {
      // ---------------- gru0, step t = u ----------------
      if (u <= 253) {
        const int jt = sub, bmB = (xg - 4) * 256;
        const unsigned short* h0r = h0L + (size_t)((u+1)&1)*HB;   // h0(u-1), local L2
        const float* s0p = P.states + (size_t)u*BATCH*32;
        f32x4 R[4]={}, Z[4]={}, NI[4]={}, NH[4]={};
        #pragma unroll
        for (int ks = 0; ks < 2; ++ks) {             // K=64: s then a
          const int kl = ks*32 + kg*8;
          bfrag a[4];
          #pragma unroll
          for (int fm = 0; fm < 4; ++fm) {
            int row = bmB + wv*64 + fm*16 + r16;
            a[fm] = (ks == 0)
              ? cvt8(&s0p[(size_t)row*32 + kg*8])
              : cvt8d(&s0p[(size_t)(BATCH + row)*32 + kg*8], &s0p[(size_t)row*32 + kg*8]);
          }
          bfrag bR = *(const bfrag*)&sm[(0*16+r16)*584 + kl];
          bfrag bZ = *(const bfrag*)&sm[(1*16+r16)*584 + kl];
          bfrag bN = *(const bfrag*)&sm[(2*16+r16)*584 + kl];
          #pragma unroll
          for (int fm = 0; fm < 4; ++fm) {
            R[fm]=MFMA(a[fm],bR,R[fm]); Z[fm]=MFMA(a[fm],bZ,Z[fm]); NI[fm]=MFMA(a[fm],bN,NI[fm]);
          }
        }
        #pragma unroll 2
        for (int kt = 0; kt < 16; ++kt) {            // K=512: h0 (plain L2)
          const int kk = kt*32 + kg*8;
          const int kl = 64 + kk;
          bfrag a[4];
          #pragma unroll
          for (int fm = 0; fm < 4; ++fm) {
            int row = bmB + wv*64 + fm*16 + r16;
            a[fm] = *(const bfrag*)&h0r[(size_t)row*512 + kk];
          }
          bfrag bR = *(const bfrag*)&sm[(0*16+r16)*584 + kl];
          bfrag bZ = *(const bfrag*)&sm[(1*16+r16)*584 + kl];
          bfrag bN = *(const bfrag*)&sm[(2*16+r16)*584 + kl];
          #pragma unroll
          for (int fm = 0; fm < 4; ++fm) {
            R[fm]=MFMA(a[fm],bR,R[fm]); Z[fm]=MFMA(a[fm],bZ,Z[fm]); NH[fm]=MFMA(a[fm],bN,NH[fm]);
          }
        }
        unsigned short* exch = sm + 28032;          // [256][16]
        #pragma unroll
        for (int fm = 0; fm < 4; ++fm)
          #pragma unroll
          for (int e = 0; e < 4; ++e) {
            int rl = wv*64 + fm*16 + kg*4 + e;
            float r  = sigm(R[fm][e] + b0);
            float zg = sigm(Z[fm][e] + b1);
            float nn = tanhf(NI[fm][e] + b2 + r*(NH[fm][e] + b3));
            float hn = (1.f - zg)*nn + zg*hs[fm][e];
            hs[fm][e] = hn;
            exch[rl*16 + r16] = f2bf(hn);
          }
        __syncthreads();
        {
          int r = tid;
          u32x4 v0 = *(const u32x4*)&exch[r*16];
          u32x4 v1 = *(const u32x4*)&exch[r*16 + 8];
          size_t off = ((size_t)(bmB + r))*512 + jt*16;
          *(u32x4*)&h0L[(size_t)(u&1)*HB + off]     = v0;     // local recurrence
          *(u32x4*)&h0L[(size_t)(u&1)*HB + off + 8] = v1;
          st16_sc1(h0G + (size_t)(u&3)*HB + off,     v0);     // cross-XCD (gru1)
          st16_sc1(h0G + (size_t)(u&3)*HB + off + 8, v1);
        }
      }
    } else if (xg == 6) {
      // ---------------- fc1, step t = u-1 ----------------
      if (u >= 1 && u <= 254) {
        const int bmB = (sub >> 3) * 128, bnB = (sub & 7) * 64;
        const unsigned short* h1r = h1G + (size_t)((u+2)&3)*HB;   // h1(u-2), L3
        const float* s0p = P.states + (size_t)(u-1)*BATCH*32;
        f32x4 acc[4][2] = {};
        const int arow = bmB + (wv>>1)*64;
        const int bcol = (wv&1)*32;
        #pragma unroll 2
        for (int kt = 0; kt < 19; ++kt) {
          const int k = kt*32 + kg*8;
          bfrag a[4];
          #pragma unroll
          for (int fm = 0; fm < 4; ++fm) {
            int row = arow + fm*16 + r16;
            int rl  = row - bmB;
            if (kt == 0)      a[fm] = cvt8(&s0p[(size_t)row*32 + k]);
            else if (kt <= 2) a[fm] = *(const bfrag*)&sm[47616 + rl*64 + (k - 32)];
            else              a[fm] = vlb(h1r + (size_t)row*512 + (k - 96));
          }
          bfrag bf0 = *(const bfrag*)&sm[(bcol      + r16)*616 + k];
          bfrag bf1 = *(const bfrag*)&sm[(bcol + 16 + r16)*616 + k];
          #pragma unroll
          for (int fm = 0; fm < 4; ++fm) {
            acc[fm][0] = MFMA(a[fm], bf0, acc[fm][0]);
            acc[fm][1] = MFMA(a[fm], bf1, acc[fm][1]);
          }
        }
        unsigned short* exch = sm + 39424;          // [128][64]
        #pragma unroll
        for (int fm = 0; fm < 4; ++fm)
          #pragma unroll
          for (int fn = 0; fn < 2; ++fn) {
            float bias = fn ? b1 : b0;
            #pragma unroll
            for (int e = 0; e < 4; ++e) {
              int rl = (wv>>1)*64 + fm*16 + kg*4 + e;
              int cl = bcol + fn*16 + r16;
              exch[rl*64 + cl] = f2bf(fmaxf(acc[fm][fn][e] + bias, 0.f));
            }
          }
        __syncthreads();
        {
          int r = tid >> 1, hc = tid & 1;
          #pragma unroll
          for (int q = 0; q < 4; ++q) {
            u32x4 v = *(const u32x4*)&exch[r*64 + hc*32 + q*8];
            st16_sc1(d1G + (size_t)((u+3)&3)*HB + ((size_t)(bmB + r))*512 + bnB + hc*32 + q*8, v);
          }
        }
        __syncthreads();
      }
    } else {
      // ---------------- fc2, step t = u-2 ----------------
      if (u >= 2 && u <= 255) {
        const int bmB = (sub >> 3) * 128, bnB = (sub & 7) * 64;
        const unsigned short* dr = d1G + (size_t)((u+2)&3)*HB;    // dh1(u-2), L3
        f32x4 acc[4][2] = {};
        const int arow = bmB + (wv>>1)*64;
        const int bcol = (wv&1)*32;
        #pragma unroll 2
        for (int kt = 0; kt < 16; ++kt) {
          const int k = kt*32 + kg*8;
          bfrag a[4];
          #pragma unroll
          for (int fm = 0; fm < 4; ++fm)
            a[fm] = vlb(dr + (size_t)(arow + fm*16 + r16)*512 + k);
          bfrag bf0 = *(const bfrag*)&sm[(bcol      + r16)*520 + k];
          bfrag bf1 = *(const bfrag*)&sm[(bcol + 16 + r16)*520 + k];
          #pragma unroll
          for (int fm = 0; fm < 4; ++fm) {
            acc[fm][0] = MFMA(a[fm], bf0, acc[fm][0]);
            acc[fm][1] = MFMA(a[fm], bf1, acc[fm][1]);
          }
        }
        unsigned short* exch = sm + 66560;          // [128][64]
        #pragma unroll
        for (int fm = 0; fm < 4; ++fm)
          #pragma unroll
          for (int fn = 0; fn < 2; ++fn) {
            float bias = fn ? b1 : b0;
            #pragma unroll
            for (int e = 0; e < 4; ++e) {
              int rl = (wv>>1)*64 + fm*16 + kg*4 + e;
              int cl = bcol + fn*16 + r16;
              exch[rl*64 + cl] = f2bf(fmaxf(acc[fm][fn][e] + bias, 0.f));
            }
          }
        __syncthreads();
        {
          int r = tid >> 1, hc = tid & 1;
          #pragma unroll
          for (int q = 0; q < 4; ++q) {
            u32x4 v = *(const u32x4*)&exch[r*64 + hc*32 + q*8];
            *(u32x4*)&d2L[(size_t)(u&1)*HB + ((size_t)(bmB + r))*512 + bnB + hc*32 + q*8] = v;
          }
        }
      }
      // ---------------- head, step t = u-3 ----------------
      if (u >= 3) {
        const int t = u - 3;
        const unsigned short* dr = d2L + (size_t)((u+1)&1)*HB;    // dh2(u-3), local L2
        f32x4 acc = {};
        #pragma unroll 2
        for (int kt = 0; kt < 16; ++kt) {
          const int k = kt*32 + kg*8;
          bfrag a = *(const bfrag*)&dr[(size_t)(sub*16 + r16)*512 + k];
          bfrag b = *(const bfrag*)&sm[33280 + (wv*16 + r16)*520 + k];
          acc = MFMA(a, b, acc);
        }
        __syncthreads();                    // fc2's exch use is done
        float* exch = (float*)(sm + 66560); // [16][66]
        const int c = wv*16 + r16;
        #pragma unroll
        for (int e = 0; e < 4; ++e)
          exch[(kg*4+e)*66 + c] = acc[e] + b2;
        __syncthreads();
        const float* s0p = P.states + (size_t)t*BATCH*32;
        #pragma unroll
        for (int e2 = 0; e2 < 2; ++e2) {
          int idx = tid*2 + e2;
          int r = idx >> 5, i = idx & 31;
          int b = sub*16 + r;
          float mean = exch[r*66 + i], lv = exch[r*66 + 32 + i];
          float av = s0p[(size_t)(BATCH + b)*32 + i] - s0p[(size_t)b*32 + i];
          float d = av - mean;
          float v = 0.5f*(d*d*__expf(-lv) + lv + LOG2PI);
          if (e2) nacc1 += v; else nacc0 += v;
        }
      }
    }

    // -------------------- publish --------------------
    __syncthreads();                      // drains plain (L2) + sc1 (L3) stores
    if (tid == 0) ASTORE(&flags[blk*16], (unsigned)(u+1));
  }

  if (xg == 7) {
    #pragma unroll
    for (int e2 = 0; e2 < 2; ++e2) {
      int idx = tid*2 + e2;
      int b = sub*16 + (idx >> 5), i = idx & 31;
      P.out[(size_t)b*32 + i] = e2 ? nacc1 : nacc0;
    }
  }
}

extern "C" void kernel_launch(void* const* d_in, const int* in_sizes, int n_in,
                              void* d_out, int out_size, void* d_ws, size_t ws_size,
                              hipStream_t stream) {
  Params P;
  P.states = (const float*)d_in[0];
  P.zin    = (const float*)d_in[1];
  P.Wih0   = (const float*)d_in[2];
  P.Whh0   = (const float*)d_in[3];
  P.bih0   = (const float*)d_in[4];
  P.bhh0   = (const float*)d_in[5];
  P.Wih1   = (const float*)d_in[6];
  P.Whh1   = (const float*)d_in[7];
  P.bih1   = (const float*)d_in[8];
  P.bhh1   = (const float*)d_in[9];
  P.Wfc1   = (const float*)d_in[10];
  P.bfc1   = (const float*)d_in[11];
  P.Wfc2   = (const float*)d_in[12];
  P.bfc2   = (const float*)d_in[13];
  P.Wmean  = (const float*)d_in[14];
  P.bmean  = (const float*)d_in[15];
  P.Wlv    = (const float*)d_in[16];
  P.blv    = (const float*)d_in[17];
  P.out = (float*)d_out;
  P.act = (unsigned short*)d_ws;

  unsigned* flags = (unsigned*)(P.act + 18*(size_t)HB);   // 16 KB

  // zero: h0G+h1G (0..8HB), h0L+h1L (12..16HB), flags, out
  hipMemsetAsync(P.act, 0, 8*(size_t)HB*sizeof(unsigned short), stream);
  hipMemsetAsync(P.act + 12*(size_t)HB, 0, 4*(size_t)HB*sizeof(unsigned short), stream);
  hipMemsetAsync(flags, 0, 256*16*sizeof(unsigned), stream);
  hipMemsetAsync(d_out, 0, (size_t)out_size*sizeof(float), stream);

  fused<<<dim3(256), dim3(256), 0, stream>>>(P, flags);
}